// Round 1
// baseline (57.947 us; speedup 1.0000x reference)
//
#include <hip/hip_runtime.h>
#include <math.h>

#define NT 256
#define NACC 16

constexpr int CN = 4;
constexpr long long SVOX = 96LL * 160 * 160;   // 2,457,600 voxels per batch item
constexpr long long VTOT = 2 * SVOX;           // 4,915,200 total voxels
constexpr double SMOOTH = 1e-5;

// Accumulator layout (16 doubles):
// 0..3  intersect[c]   (sum of probs[c] where segmask==c)
// 4..7  sumprob[c]
// 8..11 count[c]       (onehot sums)
// 12    sum of bce where edgemask==1
// 13    sum of bce where edgemask==0
// 14    pos count, 15 neg count

__global__ __launch_bounds__(NT)
void jedl_stage1(const float* __restrict__ seg, const float* __restrict__ edge,
                 const int* __restrict__ smask, const int* __restrict__ emask,
                 double* __restrict__ part) {
    float acc[NACC];
#pragma unroll
    for (int i = 0; i < NACC; ++i) acc[i] = 0.f;

    const long long ngroups = VTOT / 4;
    const long long stride = (long long)gridDim.x * NT;
    for (long long g = (long long)blockIdx.x * NT + threadIdx.x; g < ngroups; g += stride) {
        const long long v = g * 4;                  // voxel quad base
        const int b = (int)(v / SVOX);              // batch index (0/1); quads never straddle
        const long long s = v - (long long)b * SVOX;
        const float* segb = seg + (long long)b * CN * SVOX + s;
        const float4 x0 = *(const float4*)(segb);
        const float4 x1 = *(const float4*)(segb + SVOX);
        const float4 x2 = *(const float4*)(segb + 2 * SVOX);
        const float4 x3 = *(const float4*)(segb + 3 * SVOX);
        const int4   tm = *(const int4*)(smask + v);
        const float4 ex = *(const float4*)(edge + v);
        const int4   em = *(const int4*)(emask + v);

#define PROC(j) do {                                                          \
        const float a0 = x0.j, a1 = x1.j, a2 = x2.j, a3 = x3.j;               \
        const float m  = fmaxf(fmaxf(a0, a1), fmaxf(a2, a3));                 \
        const float e0 = expf(a0 - m), e1 = expf(a1 - m);                     \
        const float e2 = expf(a2 - m), e3 = expf(a3 - m);                     \
        const float inv = 1.f / (e0 + e1 + e2 + e3);                          \
        const float p0 = e0 * inv, p1 = e1 * inv, p2 = e2 * inv, p3 = e3 * inv;\
        acc[4] += p0; acc[5] += p1; acc[6] += p2; acc[7] += p3;               \
        const int t = tm.j;                                                   \
        acc[0] += (t == 0) ? p0 : 0.f;                                        \
        acc[1] += (t == 1) ? p1 : 0.f;                                        \
        acc[2] += (t == 2) ? p2 : 0.f;                                        \
        acc[3] += (t == 3) ? p3 : 0.f;                                        \
        acc[8]  += (float)(t == 0); acc[9]  += (float)(t == 1);               \
        acc[10] += (float)(t == 2); acc[11] += (float)(t == 3);               \
        const float xx = ex.j; const int tt = em.j;                           \
        const float bce = fmaxf(xx, 0.f) - xx * (float)tt                     \
                          + log1pf(expf(-fabsf(xx)));                         \
        acc[12] += (tt == 1) ? bce : 0.f;                                     \
        acc[13] += (tt == 0) ? bce : 0.f;                                     \
        acc[14] += (float)(tt == 1); acc[15] += (float)(tt == 0);             \
    } while (0)

        PROC(x); PROC(y); PROC(z); PROC(w);
#undef PROC
    }

    // wave (64-lane) shuffle reduction of all 16 accumulators
#pragma unroll
    for (int i = 0; i < NACC; ++i) {
        float v = acc[i];
        for (int off = 32; off > 0; off >>= 1) v += __shfl_down(v, off);
        acc[i] = v;
    }

    __shared__ float wpart[NT / 64][NACC];
    const int lane = threadIdx.x & 63, wid = threadIdx.x >> 6;
    if (lane == 0) {
#pragma unroll
        for (int i = 0; i < NACC; ++i) wpart[wid][i] = acc[i];
    }
    __syncthreads();
    if (threadIdx.x == 0) {
#pragma unroll
        for (int i = 0; i < NACC; ++i) {
            double s = 0.0;
            for (int w = 0; w < NT / 64; ++w) s += (double)wpart[w][i];
            part[(long long)blockIdx.x * NACC + i] = s;
        }
    }
}

__global__ __launch_bounds__(NT)
void jedl_stage2(const double* __restrict__ part, int nblocks, float* __restrict__ out) {
    __shared__ double red[NT];
    __shared__ double tot[NACC];
    const int tid = threadIdx.x;
    const int a = tid & (NACC - 1);
    double ssum = 0.0;
    for (int r = tid >> 4; r < nblocks; r += NT / NACC)
        ssum += part[(long long)r * NACC + a];
    red[tid] = ssum;
    __syncthreads();
    if (tid < NACC) {
        double t = 0.0;
        for (int k = 0; k < NT / NACC; ++k) t += red[tid + NACC * k];
        tot[tid] = t;
    }
    __syncthreads();
    if (tid == 0) {
        double dsum = 0.0;
        for (int c = 0; c < 4; ++c)
            dsum += (2.0 * tot[c] + SMOOTH) / (tot[4 + c] + tot[8 + c] + SMOOTH);
        const double region = 1.0 - dsum / 4.0;
        const double bp = tot[12], bn = tot[13], pc = tot[14], nc = tot[15];
        const double sum = pc + nc;
        const double eloss = (nc * bp + pc * bn) / (sum * (double)VTOT);
        out[0] = (float)region;
        out[1] = (float)eloss;
    }
}

extern "C" void kernel_launch(void* const* d_in, const int* in_sizes, int n_in,
                              void* d_out, int out_size, void* d_ws, size_t ws_size,
                              hipStream_t stream) {
    const float* seg   = (const float*)d_in[0];
    const float* edge  = (const float*)d_in[1];
    const int*   smask = (const int*)d_in[2];
    const int*   emask = (const int*)d_in[3];
    float* out  = (float*)d_out;
    double* part = (double*)d_ws;

    int nb = 1024;
    const size_t need = (size_t)nb * NACC * sizeof(double);
    if (ws_size < need) nb = (int)(ws_size / (NACC * sizeof(double)));
    if (nb < 1) nb = 1;

    jedl_stage1<<<nb, NT, 0, stream>>>(seg, edge, smask, emask, part);
    jedl_stage2<<<1, NT, 0, stream>>>(part, nb, out);
}